// Round 1
// baseline (3269.203 us; speedup 1.0000x reference)
//
#include <hip/hip_runtime.h>

#define BATCH 8192
#define NSTEP 29
#define BTILE 32
#define BT    512          // threads/block, 8 waves
#define GS    808          // gates LDS stride (fp32)
#define XS    72           // x buffer stride (bf16)   [32][72]
#define HS    232          // h1 buffer stride (bf16)  [32][232]
#define H2S   264          // h2|inp concat stride     [32][264]
#define OS    232          // out3 buffer stride       [32][232]

// padded bf16 weights in ws (element offsets)
#define OFF_WIH1 0              // [800][64]
#define OFF_WHH1 51200          // [800][224]
#define OFF_WIH2 230400         // [800][224]
#define OFF_WHH2 409600         // [800][224]
#define OFF_FC1  588800         // [208][256]
#define OFF_FC2  642048         // [48][224]
#define WS_TOT   652800

typedef __bf16 bf16x8 __attribute__((ext_vector_type(8)));
typedef float  f32x4  __attribute__((ext_vector_type(4)));

__device__ __forceinline__ unsigned short f2bf(float f) {
    union { float f; unsigned u; } v; v.f = f;
    unsigned r = v.u + 0x7fffu + ((v.u >> 16) & 1u);
    return (unsigned short)(r >> 16);
}
__device__ __forceinline__ float sigf(float x) { return 1.0f / (1.0f + __expf(-x)); }
__device__ __forceinline__ float tanh_(float x) {
    x = fminf(15.0f, fmaxf(-15.0f, x));
    float e = __expf(2.0f * x);
    return (e - 1.0f) / (e + 1.0f);
}

__global__ void actp_prep(const float* __restrict__ wih1, const float* __restrict__ whh1,
                          const float* __restrict__ wih2, const float* __restrict__ whh2,
                          const float* __restrict__ fc1w, const float* __restrict__ fc2w,
                          unsigned short* __restrict__ ws) {
    int i = blockIdx.x * 256 + threadIdx.x;
    if (i >= WS_TOT) return;
    unsigned short v;
    if (i < OFF_WHH1) {
        int n = i >> 6, k = i & 63;
        v = (k < 60) ? f2bf(wih1[n * 60 + k]) : (unsigned short)0;
    } else if (i < OFF_WIH2) {
        int j = i - OFF_WHH1; int n = j / 224, k = j % 224;
        v = (k < 200) ? f2bf(whh1[n * 200 + k]) : (unsigned short)0;
    } else if (i < OFF_WHH2) {
        int j = i - OFF_WIH2; int n = j / 224, k = j % 224;
        v = (k < 200) ? f2bf(wih2[n * 200 + k]) : (unsigned short)0;
    } else if (i < OFF_FC1) {
        int j = i - OFF_WHH2; int n = j / 224, k = j % 224;
        v = (k < 200) ? f2bf(whh2[n * 200 + k]) : (unsigned short)0;
    } else if (i < OFF_FC2) {
        int j = i - OFF_FC1; int n = j >> 8, k = j & 255;
        v = (n < 200 && k < 248) ? f2bf(fc1w[n * 248 + k]) : (unsigned short)0;
    } else {
        int j = i - OFF_FC2; int n = j / 224, k = j % 224;
        v = (k < 200) ? f2bf(fc2w[n * 200 + k]) : (unsigned short)0;
    }
    ws[i] = v;
}

// one N-tile (16 cols), both M-tiles (rows 0-15, 16-31); NC K-chunks of 32.
// A: lane holds A[lane&15][kc*32+(lane>>4)*8 ..+7]; B: lane holds W[n][same k]
template<int NC>
__device__ __forceinline__ void mma_part(f32x4& acc0, f32x4& acc1,
    const unsigned short* __restrict__ abuf, const int AS,
    const unsigned short* __restrict__ wrow,
    const int lrow, const int lgrp)
{
    bf16x8 bfr[NC];
#pragma unroll
    for (int kc = 0; kc < NC; ++kc)
        bfr[kc] = *(const bf16x8*)(wrow + kc * 32 + lgrp * 8);
#pragma unroll
    for (int kc = 0; kc < NC; ++kc) {
        const int koff = kc * 32 + lgrp * 8;
        bf16x8 a0 = *(const bf16x8*)(abuf + lrow * AS + koff);
        bf16x8 a1 = *(const bf16x8*)(abuf + (lrow + 16) * AS + koff);
        acc0 = __builtin_amdgcn_mfma_f32_16x16x32_bf16(a0, bfr[kc], acc0, 0, 0, 0);
        acc1 = __builtin_amdgcn_mfma_f32_16x16x32_bf16(a1, bfr[kc], acc1, 0, 0, 0);
    }
}

__global__ __launch_bounds__(BT, 1) void actp_main(
    const float* __restrict__ tact, const float* __restrict__ acts,
    const float* __restrict__ bih1, const float* __restrict__ bhh1,
    const float* __restrict__ bih2, const float* __restrict__ bhh2,
    const float* __restrict__ fc1b, const float* __restrict__ fc2b,
    const unsigned short* __restrict__ ws, float* __restrict__ out)
{
    __shared__ alignas(16) unsigned short xbuf[BTILE * XS];
    __shared__ alignas(16) unsigned short h1buf[BTILE * HS];
    __shared__ alignas(16) unsigned short h2cat[BTILE * H2S];   // [0,200)=h2, [200,248)=inp_tactile, rest 0
    __shared__ alignas(16) unsigned short o3buf[BTILE * OS];
    __shared__ float gates[BTILE * GS];

    const int tid  = threadIdx.x;
    const int lane = tid & 63;
    const int wid  = tid >> 6;      // 0..7
    const int lrow = lane & 15;
    const int lgrp = lane >> 4;     // 0..3
    const int r0   = blockIdx.x * BTILE;

    const unsigned short* wih1p = ws + OFF_WIH1;
    const unsigned short* whh1p = ws + OFF_WHH1;
    const unsigned short* wih2p = ws + OFF_WIH2;
    const unsigned short* whh2p = ws + OFF_WHH2;
    const unsigned short* wfc1p = ws + OFF_FC1;
    const unsigned short* wfc2p = ws + OFF_FC2;

    for (int i = tid; i < BTILE * XS;  i += BT) xbuf[i]  = 0;
    for (int i = tid; i < BTILE * HS;  i += BT) h1buf[i] = 0;
    for (int i = tid; i < BTILE * H2S; i += BT) h2cat[i] = 0;
    for (int i = tid; i < BTILE * OS;  i += BT) o3buf[i] = 0;
    __syncthreads();
    // state = actions[0] -> x cols 54..59 (constant over steps)
    for (int i = tid; i < BTILE * 6; i += BT) {
        int b = i / 6, m = i - b * 6;
        xbuf[b * XS + 54 + m] = f2bf(acts[(size_t)(r0 + b) * 6 + m]);
    }

    float c1[13], c2[13];
#pragma unroll
    for (int k = 0; k < 13; ++k) { c1[k] = 0.0f; c2[k] = 0.0f; }

    for (int idx = 0; idx < NSTEP; ++idx) {
        // ---- phase 0: inputs ----
        if (idx <= 9) {   // ground-truth tactile
            for (int i = tid; i < BTILE * 48; i += BT) {
                int b = i / 48, j = i - b * 48;
                unsigned short v = f2bf(tact[((size_t)idx * BATCH + r0 + b) * 48 + j]);
                xbuf[b * XS + j] = v;
                h2cat[b * H2S + 200 + j] = v;
            }
        }
        for (int i = tid; i < BTILE * 6; i += BT) {
            int b = i / 6, m = i - b * 6;
            xbuf[b * XS + 48 + m] = f2bf(acts[((size_t)(idx + 1) * BATCH + r0 + b) * 6 + m]);
        }
        __syncthreads();

        // ---- GEMM1: gates = x@Wih1^T + h1@Whh1^T ----
        for (int nt = wid; nt < 50; nt += 8) {
            const int n = nt * 16 + lrow;
            f32x4 acc0 = {0.f, 0.f, 0.f, 0.f}, acc1 = {0.f, 0.f, 0.f, 0.f};
            mma_part<2>(acc0, acc1, xbuf,  XS, wih1p + n * 64,  lrow, lgrp);
            mma_part<7>(acc0, acc1, h1buf, HS, whh1p + n * 224, lrow, lgrp);
#pragma unroll
            for (int r = 0; r < 4; ++r) {
                gates[(lgrp * 4 + r) * GS + n]        = acc0[r];
                gates[(lgrp * 4 + r + 16) * GS + n]   = acc1[r];
            }
        }
        __syncthreads();

        // ---- LSTM1 elementwise ----
#pragma unroll
        for (int k = 0; k < 13; ++k) {
            int e = tid + k * BT;
            if (e < BTILE * 200) {
                int b = e / 200, j = e - b * 200;
                float gi = gates[b * GS + j]       + bih1[j]       + bhh1[j];
                float gf = gates[b * GS + 200 + j] + bih1[200 + j] + bhh1[200 + j];
                float gg = gates[b * GS + 400 + j] + bih1[400 + j] + bhh1[400 + j];
                float go = gates[b * GS + 600 + j] + bih1[600 + j] + bhh1[600 + j];
                float c = sigf(gf) * c1[k] + sigf(gi) * tanh_(gg);
                c1[k] = c;
                h1buf[b * HS + j] = f2bf(sigf(go) * tanh_(c));
            }
        }
        __syncthreads();

        // ---- GEMM2: gates = h1@Wih2^T + h2@Whh2^T ----
        for (int nt = wid; nt < 50; nt += 8) {
            const int n = nt * 16 + lrow;
            f32x4 acc0 = {0.f, 0.f, 0.f, 0.f}, acc1 = {0.f, 0.f, 0.f, 0.f};
            mma_part<7>(acc0, acc1, h1buf, HS,  wih2p + n * 224, lrow, lgrp);
            mma_part<7>(acc0, acc1, h2cat, H2S, whh2p + n * 224, lrow, lgrp);
#pragma unroll
            for (int r = 0; r < 4; ++r) {
                gates[(lgrp * 4 + r) * GS + n]        = acc0[r];
                gates[(lgrp * 4 + r + 16) * GS + n]   = acc1[r];
            }
        }
        __syncthreads();

        // ---- LSTM2 elementwise ----
#pragma unroll
        for (int k = 0; k < 13; ++k) {
            int e = tid + k * BT;
            if (e < BTILE * 200) {
                int b = e / 200, j = e - b * 200;
                float gi = gates[b * GS + j]       + bih2[j]       + bhh2[j];
                float gf = gates[b * GS + 200 + j] + bih2[200 + j] + bhh2[200 + j];
                float gg = gates[b * GS + 400 + j] + bih2[400 + j] + bhh2[400 + j];
                float go = gates[b * GS + 600 + j] + bih2[600 + j] + bhh2[600 + j];
                float c = sigf(gf) * c2[k] + sigf(gi) * tanh_(gg);
                c2[k] = c;
                h2cat[b * H2S + j] = f2bf(sigf(go) * tanh_(c));
            }
        }
        __syncthreads();

        // ---- FC1: [32,256(=h2|inp|0)] @ fc1^T -> gates[:,0:208) ----
        for (int nt = wid; nt < 13; nt += 8) {
            const int n = nt * 16 + lrow;
            f32x4 acc0 = {0.f, 0.f, 0.f, 0.f}, acc1 = {0.f, 0.f, 0.f, 0.f};
            mma_part<8>(acc0, acc1, h2cat, H2S, wfc1p + n * 256, lrow, lgrp);
#pragma unroll
            for (int r = 0; r < 4; ++r) {
                gates[(lgrp * 4 + r) * GS + n]        = acc0[r];
                gates[(lgrp * 4 + r + 16) * GS + n]   = acc1[r];
            }
        }
        __syncthreads();

        // ---- FC1 elementwise: out3 = tanh(. + b) ----
#pragma unroll
        for (int k = 0; k < 13; ++k) {
            int e = tid + k * BT;
            if (e < BTILE * 200) {
                int b = e / 200, j = e - b * 200;
                o3buf[b * OS + j] = f2bf(tanh_(gates[b * GS + j] + fc1b[j]));
            }
        }
        __syncthreads();

        // ---- FC2: [32,224(=out3|0)] @ fc2^T -> gates[:,0:48) ----
        for (int nt = wid; nt < 3; nt += 8) {
            const int n = nt * 16 + lrow;
            f32x4 acc0 = {0.f, 0.f, 0.f, 0.f}, acc1 = {0.f, 0.f, 0.f, 0.f};
            mma_part<7>(acc0, acc1, o3buf, OS, wfc2p + n * 224, lrow, lgrp);
#pragma unroll
            for (int r = 0; r < 4; ++r) {
                gates[(lgrp * 4 + r) * GS + n]        = acc0[r];
                gates[(lgrp * 4 + r + 16) * GS + n]   = acc1[r];
            }
        }
        __syncthreads();

        // ---- FC2 elementwise: out4 = tanh(. + b); emit + feedback ----
#pragma unroll
        for (int k = 0; k < 3; ++k) {
            int e = tid + k * BT;   // < 1536 always
            int b = e / 48, j = e - b * 48;
            float o4 = tanh_(gates[b * GS + j] + fc2b[j]);
            if (idx >= 9) {
                out[((size_t)(idx - 9) * BATCH + r0 + b) * 48 + j] = o4;
                unsigned short v = f2bf(o4);
                xbuf[b * XS + j] = v;            // next-step LSTM input
                h2cat[b * H2S + 200 + j] = v;    // next-step fc1 concat input
            }
        }
        __syncthreads();
    }
}

extern "C" void kernel_launch(void* const* d_in, const int* in_sizes, int n_in,
                              void* d_out, int out_size, void* d_ws, size_t ws_size,
                              hipStream_t stream) {
    (void)in_sizes; (void)n_in; (void)out_size; (void)ws_size;
    const float* tact = (const float*)d_in[0];
    const float* acts = (const float*)d_in[1];
    const float* wih1 = (const float*)d_in[2];
    const float* whh1 = (const float*)d_in[3];
    const float* bih1 = (const float*)d_in[4];
    const float* bhh1 = (const float*)d_in[5];
    const float* wih2 = (const float*)d_in[6];
    const float* whh2 = (const float*)d_in[7];
    const float* bih2 = (const float*)d_in[8];
    const float* bhh2 = (const float*)d_in[9];
    const float* fc1w = (const float*)d_in[10];
    const float* fc1b = (const float*)d_in[11];
    const float* fc2w = (const float*)d_in[12];
    const float* fc2b = (const float*)d_in[13];
    unsigned short* ws = (unsigned short*)d_ws;
    float* outp = (float*)d_out;

    actp_prep<<<WS_TOT / 256, 256, 0, stream>>>(wih1, whh1, wih2, whh2, fc1w, fc2w, ws);
    actp_main<<<BATCH / BTILE, BT, 0, stream>>>(tact, acts, bih1, bhh1, bih2, bhh2,
                                                fc1b, fc2b, ws, outp);
}

// Round 2
// 1804.365 us; speedup vs baseline: 1.8118x; 1.8118x over previous
//
#include <hip/hip_runtime.h>

#define BATCH 8192
#define NSTEP 29
#define BTILE 32
#define BT    512          // 8 waves
#define XS    72           // x buffer stride (bf16): [0,48)=tactile/out4, [48,54)=act, [54,60)=state, [60]=1, rest 0
#define HS    232          // h1 stride: [0,208) h (200 real + 8 zero), [208]=1, rest 0
#define H2S   296          // h2cat stride: [0,208) h2, [208,256) inp, [256]=1, rest 0
#define OS    232          // o3 stride: [0,208) o3, [208]=1, rest 0

#define G1S   59904        // 208*288  (gate stride, W1)
#define G2S   93184        // 208*448  (gate stride, W2)
#define OW1   0            // W1: [4][208][288]  K: [0,64)=x, [64,288)=h1_old
#define OW2   239616       // W2: [4][208][448]  K: [0,224)=h1_new, [224,448)=h2_old
#define OF1   612352       // FC1: [208][288]    K: [0,200)=h2, [208,256)=inp, [256]=bias
#define OF2   672256       // FC2: [48][224]     K: [0,200)=o3, [208]=bias
#define WTOT  683008

typedef __bf16 bf16x8 __attribute__((ext_vector_type(8)));
typedef float  f32x4  __attribute__((ext_vector_type(4)));

__device__ __forceinline__ unsigned short f2bf(float f) {
    union { float f; unsigned u; } v; v.f = f;
    unsigned r = v.u + 0x7fffu + ((v.u >> 16) & 1u);
    return (unsigned short)(r >> 16);
}
__device__ __forceinline__ float sigf(float x) { return 1.0f / (1.0f + __expf(-x)); }
__device__ __forceinline__ float tanh_(float x) {
    x = fminf(15.0f, fmaxf(-15.0f, x));
    float e = __expf(2.0f * x);
    return (e - 1.0f) / (e + 1.0f);
}

// ---- weight repack: gate-blocked, K-concatenated, bias folded as a K-column, bf16 ----
__global__ void actp_prep(const float* __restrict__ wih1, const float* __restrict__ whh1,
                          const float* __restrict__ bih1, const float* __restrict__ bhh1,
                          const float* __restrict__ wih2, const float* __restrict__ whh2,
                          const float* __restrict__ bih2, const float* __restrict__ bhh2,
                          const float* __restrict__ fc1w, const float* __restrict__ fc1b,
                          const float* __restrict__ fc2w, const float* __restrict__ fc2b,
                          unsigned short* __restrict__ ws) {
    int i = blockIdx.x * 256 + threadIdx.x;
    if (i >= WTOT) return;
    float v = 0.f;
    if (i < OW2) {                              // W1 [4][208][288]
        int g = i / G1S; int rem = i - g * G1S; int n = rem / 288; int k = rem - n * 288;
        if (n < 200) {
            int orig = g * 200 + n;
            if (k < 60)                 v = wih1[orig * 60 + k];
            else if (k == 60)           v = bih1[orig] + bhh1[orig];
            else if (k >= 64 && k < 264) v = whh1[orig * 200 + (k - 64)];
        }
    } else if (i < OF1) {                       // W2 [4][208][448]
        int j2 = i - OW2; int g = j2 / G2S; int rem = j2 - g * G2S; int n = rem / 448; int k = rem - n * 448;
        if (n < 200) {
            int orig = g * 200 + n;
            if (k < 200)                  v = wih2[orig * 200 + k];
            else if (k == 208)            v = bih2[orig] + bhh2[orig];
            else if (k >= 224 && k < 424) v = whh2[orig * 200 + (k - 224)];
        }
    } else if (i < OF2) {                       // FC1 [208][288]
        int j2 = i - OF1; int n = j2 / 288; int k = j2 - n * 288;
        if (n < 200) {
            if (k < 200)                  v = fc1w[n * 248 + k];
            else if (k >= 208 && k < 256) v = fc1w[n * 248 + 200 + (k - 208)];
            else if (k == 256)            v = fc1b[n];
        }
    } else {                                    // FC2 [48][224]
        int j2 = i - OF2; int n = j2 / 224; int k = j2 - n * 224;
        if (k < 200)       v = fc2w[n * 200 + k];
        else if (k == 208) v = fc2b[n];
    }
    ws[i] = (v == 0.f) ? (unsigned short)0 : f2bf(v);
}

// 4-gate MFMA tile + in-register LSTM elementwise. A spans two LDS buffers
// (kc < SPLIT from a0buf, else a1buf at koff-KOFF1). c-state stays in VGPRs.
template<int NKC, int SPLIT, int SA0, int SA1, int KOFF1>
__device__ __forceinline__ void lstm_tile(
    const unsigned short* a0buf, const unsigned short* a1buf,
    const unsigned short* bp, const int gstride,
    const int lrow, const int lgrp,
    float (&cst)[2][4],
    unsigned short* hout, const int hstride, const int jcol)
{
    f32x4 acc[4][2];
#pragma unroll
    for (int g = 0; g < 4; ++g) { acc[g][0] = {0.f,0.f,0.f,0.f}; acc[g][1] = {0.f,0.f,0.f,0.f}; }
#pragma unroll
    for (int kc = 0; kc < NKC; ++kc) {
        const int koff = kc * 32 + lgrp * 8;
        bf16x8 a0, a1;
        if (kc < SPLIT) {
            a0 = *(const bf16x8*)(a0buf + lrow * SA0 + koff);
            a1 = *(const bf16x8*)(a0buf + (lrow + 16) * SA0 + koff);
        } else {
            a0 = *(const bf16x8*)(a1buf + lrow * SA1 + koff - KOFF1);
            a1 = *(const bf16x8*)(a1buf + (lrow + 16) * SA1 + koff - KOFF1);
        }
#pragma unroll
        for (int g = 0; g < 4; ++g) {
            bf16x8 b = *(const bf16x8*)(bp + g * gstride + koff);
            acc[g][0] = __builtin_amdgcn_mfma_f32_16x16x32_bf16(a0, b, acc[g][0], 0, 0, 0);
            acc[g][1] = __builtin_amdgcn_mfma_f32_16x16x32_bf16(a1, b, acc[g][1], 0, 0, 0);
        }
    }
#pragma unroll
    for (int m = 0; m < 2; ++m)
#pragma unroll
    for (int r = 0; r < 4; ++r) {
        float c = sigf(acc[1][m][r]) * cst[m][r] + sigf(acc[0][m][r]) * tanh_(acc[2][m][r]);
        cst[m][r] = c;
        hout[(m * 16 + lgrp * 4 + r) * hstride + jcol] = f2bf(sigf(acc[3][m][r]) * tanh_(c));
    }
}

__global__ __launch_bounds__(BT, 2) void actp_main(
    const float* __restrict__ tact, const float* __restrict__ acts,
    const unsigned short* __restrict__ ws, float* __restrict__ out)
{
    __shared__ alignas(16) unsigned short xbuf[BTILE * XS];
    __shared__ alignas(16) unsigned short h1buf[2][BTILE * HS];
    __shared__ alignas(16) unsigned short h2cat[2][BTILE * H2S];
    __shared__ alignas(16) unsigned short o3buf[BTILE * OS];

    const int tid  = threadIdx.x;
    const int lane = tid & 63;
    const int wid  = tid >> 6;
    const int lrow = lane & 15;
    const int lgrp = lane >> 4;
    const int r0   = blockIdx.x * BTILE;

    // ---- prologue: zero, bias columns, step-0 inputs ----
    for (int i = tid; i < BTILE * XS;      i += BT) xbuf[i] = 0;
    for (int i = tid; i < 2 * BTILE * HS;  i += BT) h1buf[0][i] = 0;
    for (int i = tid; i < 2 * BTILE * H2S; i += BT) h2cat[0][i] = 0;
    for (int i = tid; i < BTILE * OS;      i += BT) o3buf[i] = 0;
    __syncthreads();
    if (tid < BTILE) {
        const unsigned short ONE = 0x3F80;
        xbuf[tid * XS + 60] = ONE;
        h1buf[0][tid * HS + 208] = ONE;  h1buf[1][tid * HS + 208] = ONE;
        h2cat[0][tid * H2S + 256] = ONE; h2cat[1][tid * H2S + 256] = ONE;
        o3buf[tid * OS + 208] = ONE;
    }
    if (tid < BTILE * 6) {
        int b = tid / 6, m = tid - b * 6;
        xbuf[b * XS + 54 + m] = f2bf(acts[(size_t)(r0 + b) * 6 + m]);                     // state = acts[0]
        xbuf[b * XS + 48 + m] = f2bf(acts[((size_t)1 * BATCH + r0 + b) * 6 + m]);         // action for step 0
    }
    for (int i = tid; i < BTILE * 48; i += BT) {
        int b = i / 48, j = i - b * 48;
        unsigned short v = f2bf(tact[(size_t)(r0 + b) * 48 + j]);                          // tact[0]
        xbuf[b * XS + j] = v;
        h2cat[0][b * H2S + 208 + j] = v;
    }
    __syncthreads();

    float c1[2][2][4], c2[2][2][4];
#pragma unroll
    for (int t = 0; t < 2; ++t)
#pragma unroll
    for (int m = 0; m < 2; ++m)
#pragma unroll
    for (int r = 0; r < 4; ++r) { c1[t][m][r] = 0.f; c2[t][m][r] = 0.f; }

    for (int idx = 0; idx < NSTEP; ++idx) {
        const int p = idx & 1;
        unsigned short* h1n = h1buf[p];
        unsigned short* h1o = h1buf[p ^ 1];
        unsigned short* h2n = h2cat[p];
        unsigned short* h2o = h2cat[p ^ 1];

        // ---- P1: LSTM1 (x | h1_old) -> h1_new ----
#pragma unroll
        for (int t = 0; t < 2; ++t) {
            const int jt = wid + 8 * t;
            if (jt < 13) {
                const int n = jt * 16 + lrow;
                lstm_tile<9, 2, XS, HS, 64>(xbuf, h1o, ws + OW1 + (unsigned)n * 288, G1S,
                                            lrow, lgrp, c1[t], h1n, HS, n);
            }
        }
        __syncthreads();

        // ---- P2: LSTM2 (h1_new | h2_old) -> h2_new ----
#pragma unroll
        for (int t = 0; t < 2; ++t) {
            const int jt = wid + 8 * t;
            if (jt < 13) {
                const int n = jt * 16 + lrow;
                lstm_tile<14, 7, HS, H2S, 224>(h1n, h2o, ws + OW2 + (unsigned)n * 448, G2S,
                                               lrow, lgrp, c2[t], h2n, H2S, n);
            }
        }
        __syncthreads();

        // ---- P3: FC1 (h2_new|inp|1) -> o3 ; plus next-step input preloads ----
#pragma unroll
        for (int t = 0; t < 2; ++t) {
            const int jt = wid + 8 * t;
            if (jt < 13) {
                const int n = jt * 16 + lrow;
                const unsigned short* bp = ws + OF1 + (unsigned)n * 288;
                f32x4 a0c = {0.f,0.f,0.f,0.f}, a1c = {0.f,0.f,0.f,0.f};
#pragma unroll
                for (int kc = 0; kc < 9; ++kc) {
                    const int koff = kc * 32 + lgrp * 8;
                    bf16x8 a0 = *(const bf16x8*)(h2n + lrow * H2S + koff);
                    bf16x8 a1 = *(const bf16x8*)(h2n + (lrow + 16) * H2S + koff);
                    bf16x8 b  = *(const bf16x8*)(bp + koff);
                    a0c = __builtin_amdgcn_mfma_f32_16x16x32_bf16(a0, b, a0c, 0, 0, 0);
                    a1c = __builtin_amdgcn_mfma_f32_16x16x32_bf16(a1, b, a1c, 0, 0, 0);
                }
#pragma unroll
                for (int r = 0; r < 4; ++r) {
                    o3buf[(lgrp * 4 + r) * OS + n]      = f2bf(tanh_(a0c[r]));
                    o3buf[(16 + lgrp * 4 + r) * OS + n] = f2bf(tanh_(a1c[r]));
                }
            }
        }
        if (idx < NSTEP - 1) {
            if (tid < BTILE * 6) {           // action for step idx+1 = acts[idx+2]
                int b = tid / 6, m = tid - b * 6;
                xbuf[b * XS + 48 + m] = f2bf(acts[((size_t)(idx + 2) * BATCH + r0 + b) * 6 + m]);
            }
            if (idx < 9) {                   // ground-truth tactile for step idx+1
                for (int i = tid; i < BTILE * 48; i += BT) {
                    int b = i / 48, j = i - b * 48;
                    unsigned short v = f2bf(tact[((size_t)(idx + 1) * BATCH + r0 + b) * 48 + j]);
                    xbuf[b * XS + j] = v;
                    h2cat[p ^ 1][b * H2S + 208 + j] = v;
                }
            }
        }
        __syncthreads();

        // ---- P4: FC2 (o3|1) -> out4 ; emit + feedback ----
        if (wid < 3) {
            const int n = wid * 16 + lrow;   // 0..47
            const unsigned short* bp = ws + OF2 + (unsigned)n * 224;
            f32x4 a0c = {0.f,0.f,0.f,0.f}, a1c = {0.f,0.f,0.f,0.f};
#pragma unroll
            for (int kc = 0; kc < 7; ++kc) {
                const int koff = kc * 32 + lgrp * 8;
                bf16x8 a0 = *(const bf16x8*)(o3buf + lrow * OS + koff);
                bf16x8 a1 = *(const bf16x8*)(o3buf + (lrow + 16) * OS + koff);
                bf16x8 b  = *(const bf16x8*)(bp + koff);
                a0c = __builtin_amdgcn_mfma_f32_16x16x32_bf16(a0, b, a0c, 0, 0, 0);
                a1c = __builtin_amdgcn_mfma_f32_16x16x32_bf16(a1, b, a1c, 0, 0, 0);
            }
            if (idx >= 9) {
#pragma unroll
                for (int m = 0; m < 2; ++m)
#pragma unroll
                for (int r = 0; r < 4; ++r) {
                    const int row = m * 16 + lgrp * 4 + r;
                    float o4 = tanh_(m == 0 ? a0c[r] : a1c[r]);
                    out[((size_t)(idx - 9) * BATCH + r0 + row) * 48 + n] = o4;
                    unsigned short v = f2bf(o4);
                    xbuf[row * XS + n] = v;              // next-step LSTM input
                    h2cat[p ^ 1][row * H2S + 208 + n] = v;  // next-step FC1 concat input
                }
            }
        }
        __syncthreads();
    }
}

extern "C" void kernel_launch(void* const* d_in, const int* in_sizes, int n_in,
                              void* d_out, int out_size, void* d_ws, size_t ws_size,
                              hipStream_t stream) {
    (void)in_sizes; (void)n_in; (void)out_size; (void)ws_size;
    const float* tact = (const float*)d_in[0];
    const float* acts = (const float*)d_in[1];
    const float* wih1 = (const float*)d_in[2];
    const float* whh1 = (const float*)d_in[3];
    const float* bih1 = (const float*)d_in[4];
    const float* bhh1 = (const float*)d_in[5];
    const float* wih2 = (const float*)d_in[6];
    const float* whh2 = (const float*)d_in[7];
    const float* bih2 = (const float*)d_in[8];
    const float* bhh2 = (const float*)d_in[9];
    const float* fc1w = (const float*)d_in[10];
    const float* fc1b = (const float*)d_in[11];
    const float* fc2w = (const float*)d_in[12];
    const float* fc2b = (const float*)d_in[13];
    unsigned short* ws = (unsigned short*)d_ws;
    float* outp = (float*)d_out;

    actp_prep<<<(WTOT + 255) / 256, 256, 0, stream>>>(wih1, whh1, bih1, bhh1,
                                                      wih2, whh2, bih2, bhh2,
                                                      fc1w, fc1b, fc2w, fc2b, ws);
    actp_main<<<BATCH / BTILE, BT, 0, stream>>>(tact, acts, ws, outp);
}